// Round 4
// baseline (188.069 us; speedup 1.0000x reference)
//
#include <hip/hip_runtime.h>
#include <hip/hip_bf16.h>

// Problem constants (fixed by reference setup_inputs)
constexpr int NWIN = 49;     // 7x7 windows
constexpr int QLD  = 52;     // padded row length for 49-length rows (13 float4)
constexpr int XLD  = 68;     // chain LDS tile stride (2-way conflict = free)

// workspace layout (float offsets)
constexpr int OFF_WS   = 0;            // [8][64][52]      = 26624 (bt, s, win)
constexpr int OFF_Q    = 26624;        // [2][128][4][52]  = 53248 (b, d, t, n)
constexpr int OFF_A12  = 79872;        // [2][3][64][64]
constexpr int OFF_A12T = 104448;
constexpr int OFF_A21  = 129024;
constexpr int OFF_A21T = 153600;       // end = 178176 floats (~713 KB)

// ---------------------------------------------------------------------------
// K1: fused front end — blocks [0,392): scatter; blocks [392,490): q head.
// The two stages are data-independent and now run concurrently.
__global__ void __launch_bounds__(256, 1)
k_front(const int* __restrict__ mask, const float* __restrict__ feats,
        const float* __restrict__ Wh, float* __restrict__ ws, float* __restrict__ q) {
    if (blockIdx.x < 392) {
        // ---- scatter: ws[bt][s][win] = sum over window pixels with label s of 1/sm.
        // sum_win ws[bt][s][:] == pixel count of label s (coverage * 1/sm == 1),
        // so the qsp denominator is just the row sum. Pad cols 49..51 zeroed.
        int win = blockIdx.x % NWIN;
        int bt  = blockIdx.x / NWIN;
        int wy = win / 7, wx = win % 7;
        __shared__ float loc[64];
        if (threadIdx.x < 64) loc[threadIdx.x] = 0.f;
        __syncthreads();
        const int* base = mask + bt * 65536 + (wy * 32) * 256 + wx * 32;
        #pragma unroll
        for (int it = 0; it < 16; ++it) {
            int idx = it * 256 + (int)threadIdx.x;
            int r = idx >> 6, c = idx & 63;
            int s = base[r * 256 + c];
            int y = wy * 32 + r, x = wx * 32 + c;
            float w = 1.f;
            if (y >= 32 && y < 224) w *= 0.5f;   // row coverage = 2
            if (x >= 32 && x < 224) w *= 0.5f;   // col coverage = 2
            atomicAdd(&loc[s], w);
        }
        __syncthreads();
        if (threadIdx.x < 64) {
            ws[(bt * 64 + (int)threadIdx.x) * QLD + win] = loc[threadIdx.x];
        } else if (win == 0) {
            int s = threadIdx.x & 63;
            int col = 49 + (int)(threadIdx.x >> 6) - 1;   // 49,50,51
            ws[(bt * 64 + s) * QLD + col] = 0.f;
        }
    } else {
        // ---- q head: q[b][d][t][n] = normalize_d(feats[b,n,:,t] @ Wh[:,d])
        int bid = blockIdx.x - 392;
        int n = bid % NWIN, b = bid / NWIN;
        __shared__ float4 f4[512];        // feats[c][t] as float4 over t
        __shared__ float4 psum4[256];
        __shared__ float4 red4[2];
        const float4* fp4 = (const float4*)(feats + (size_t)(b * NWIN + n) * 2048);
        for (int i = threadIdx.x; i < 512; i += 256) f4[i] = fp4[i];
        __syncthreads();

        int d = threadIdx.x & 127, ch = threadIdx.x >> 7;
        float a0 = 0.f, a1 = 0.f, a2 = 0.f, a3 = 0.f;
        const float* wp = Wh + d;
        int c0 = ch * 256;
        #pragma unroll 8
        for (int c = c0; c < c0 + 256; ++c) {
            float w = wp[c * 128];
            float4 fv = f4[c];
            a0 += fv.x * w; a1 += fv.y * w; a2 += fv.z * w; a3 += fv.w * w;
        }
        psum4[threadIdx.x] = make_float4(a0, a1, a2, a3);
        __syncthreads();

        float4 A;
        if (threadIdx.x < 128) {
            float4 p0 = psum4[threadIdx.x], p1 = psum4[128 + threadIdx.x];
            A = make_float4(p0.x + p1.x, p0.y + p1.y, p0.z + p1.z, p0.w + p1.w);
            float sx = A.x * A.x, sy = A.y * A.y, sz = A.z * A.z, sw = A.w * A.w;
            for (int off = 32; off; off >>= 1) {
                sx += __shfl_down(sx, off); sy += __shfl_down(sy, off);
                sz += __shfl_down(sz, off); sw += __shfl_down(sw, off);
            }
            if ((threadIdx.x & 63) == 0) red4[threadIdx.x >> 6] = make_float4(sx, sy, sz, sw);
        }
        __syncthreads();
        if (threadIdx.x < 128) {
            float4 r0 = red4[0], r1 = red4[1];
            float ix = 1.f / fmaxf(sqrtf(r0.x + r1.x), 1e-12f);
            float iy = 1.f / fmaxf(sqrtf(r0.y + r1.y), 1e-12f);
            float iz = 1.f / fmaxf(sqrtf(r0.z + r1.z), 1e-12f);
            float iw = 1.f / fmaxf(sqrtf(r0.w + r1.w), 1e-12f);
            float* qb = q + (size_t)(b * 128 + d) * 4 * QLD + n;
            qb[0 * QLD] = A.x * ix;
            qb[1 * QLD] = A.y * iy;
            qb[2 * QLD] = A.z * iz;
            qb[3 * QLD] = A.w * iw;
        }
    }
}

// ---------------------------------------------------------------------------
// K2: fused qsp + As + zero_softmax. grid = 6 (b, t-pair), block = 256.
// qsp slices computed in-block: lane = s holds its ws rows (t, t+1) in
// registers; q rows arrive as wave-broadcast float4. Results go straight
// into XOR-swizzled LDS [s][d] (exactly 64 KB), then one k=128 4x4-tile mm.
__global__ void __launch_bounds__(256, 1)
k_as(const float* __restrict__ q, const float* __restrict__ wsg,
     float* __restrict__ a12, float* __restrict__ a12T,
     float* __restrict__ a21, float* __restrict__ a21T, float* __restrict__ out) {
    int t = blockIdx.x % 3, b = blockIdx.x / 3;
    if (blockIdx.x == 0 && threadIdx.x == 0) out[0] = 0.f;   // loss accumulator
    __shared__ float4 qaT4[64 * 32];   // [s][d-swizzled]
    __shared__ float4 qbT4[64 * 32];
    const int tid = threadIdx.x;
    const int wv = tid >> 6, s = tid & 63;

    // ws rows for slices t and t+1, kept in registers (pads are zero)
    float4 wa[13], wb[13];
    float denA = 0.f, denB = 0.f;
    {
        const float4* wra = (const float4*)(wsg + (size_t)((b * 4 + t) * 64 + s) * QLD);
        const float4* wrb = (const float4*)(wsg + (size_t)((b * 4 + t + 1) * 64 + s) * QLD);
        #pragma unroll
        for (int i = 0; i < 13; ++i) {
            wa[i] = wra[i]; wb[i] = wrb[i];
            denA += wa[i].x + wa[i].y + wa[i].z + wa[i].w;
            denB += wb[i].x + wb[i].y + wb[i].z + wb[i].w;
        }
    }
    const float invA = 1.f / (denA + 1e-20f);
    const float invB = 1.f / (denB + 1e-20f);

    // qsp: wave wv covers d in [32wv, 32wv+32); write float4 per 4 d's
    const float4* q4 = (const float4*)q;
    for (int d0 = 32 * wv; d0 < 32 * wv + 32; d0 += 4) {
        float oa[4], ob[4];
        #pragma unroll
        for (int u = 0; u < 4; ++u) {
            int d = d0 + u;
            const float4* qa  = q4 + (size_t)((b * 128 + d) * 4 + t) * 13;
            const float4* qbp = q4 + (size_t)((b * 128 + d) * 4 + t + 1) * 13;
            float sa = 0.f, sb = 0.f;
            #pragma unroll
            for (int i = 0; i < 13; ++i) {
                float4 va = qa[i];
                sa += va.x * wa[i].x + va.y * wa[i].y + va.z * wa[i].z + va.w * wa[i].w;
            }
            #pragma unroll
            for (int i = 0; i < 13; ++i) {
                float4 vb = qbp[i];
                sb += vb.x * wb[i].x + vb.y * wb[i].y + vb.z * wb[i].z + vb.w * wb[i].w;
            }
            oa[u] = sa * invA; ob[u] = sb * invB;
        }
        int g = d0 >> 2;
        qaT4[s * 32 + (g ^ (s & 31))] = make_float4(oa[0], oa[1], oa[2], oa[3]);
        qbT4[s * 32 + (g ^ (s & 31))] = make_float4(ob[0], ob[1], ob[2], ob[3]);
    }
    __syncthreads();

    // As[n,m] = sum_d qspA[d,n] * qspB[d,m]  (k = 128)
    const int nl = tid >> 4, ml = tid & 15;
    float acc[16];
    #pragma unroll
    for (int i = 0; i < 16; ++i) acc[i] = 0.f;
    #pragma unroll 8
    for (int k4 = 0; k4 < 32; ++k4) {
        float4 av[4], bv[4];
        #pragma unroll
        for (int i = 0; i < 4; ++i) { int n = nl + 16 * i; av[i] = qaT4[n * 32 + (k4 ^ (n & 31))]; }
        #pragma unroll
        for (int j = 0; j < 4; ++j) { int m = ml + 16 * j; bv[j] = qbT4[m * 32 + (k4 ^ (m & 31))]; }
        #pragma unroll
        for (int i = 0; i < 4; ++i)
            #pragma unroll
            for (int j = 0; j < 4; ++j)
                acc[i * 4 + j] += av[i].x * bv[j].x + av[i].y * bv[j].y
                                + av[i].z * bv[j].z + av[i].w * bv[j].w;
    }
    __syncthreads();

    // zero_softmax both ways; emit a12, a12T, a21, a21T
    float* eb = (float*)qaT4;          // [64][65]
    float* rs = (float*)qbT4;          // [64]
    float* cs = rs + 64;               // [64]
    #pragma unroll
    for (int i = 0; i < 4; ++i)
        #pragma unroll
        for (int j = 0; j < 4; ++j) {
            int n = nl + 16 * i, m = ml + 16 * j;
            float x = acc[i * 4 + j] * (1.f / 0.07f);
            float e = expf(x) - 1.f;
            eb[n * 65 + m] = e * e;
        }
    __syncthreads();
    if (tid < 128) {
        int r = tid & 63; bool isrow = tid < 64;
        float a = 0.f;
        #pragma unroll
        for (int k = 0; k < 64; ++k) a += isrow ? eb[r * 65 + k] : eb[k * 65 + r];
        (isrow ? rs : cs)[r] = a + 1e-5f;
    }
    __syncthreads();
    float* p12  = a12  + (b * 3 + t) * 4096;
    float* p12T = a12T + (b * 3 + t) * 4096;
    float* p21  = a21  + (b * 3 + t) * 4096;
    float* p21T = a21T + (b * 3 + t) * 4096;
    #pragma unroll
    for (int i = 0; i < 4; ++i)
        #pragma unroll
        for (int j = 0; j < 4; ++j) {
            int n = nl + 16 * i, m = ml + 16 * j;
            float v   = eb[n * 65 + m];
            float v12 = v / rs[n];           // A12[n][m]
            float v21 = v / cs[m];           // A21[m][n]
            p12 [n * 64 + m] = v12;
            p12T[m * 64 + n] = v12;
            p21 [m * 64 + n] = v21;
            p21T[n * 64 + m] = v21;          // A21^T[n][m]
        }
}

// ---------------------------------------------------------------------------
// K3: chain matmuls, depth 3 via parallel half-block subchains.
// half-mm (128 threads, 4x8 tiles): operands from global (L2-hot) or LDS.
__device__ __forceinline__ void mmh_acc(float* acc, const float* Ra, int lda,
                                        const float* Rb, int ldb) {
    int lt = threadIdx.x & 127;
    int nl = lt >> 3, ml = lt & 7;
    #pragma unroll 4
    for (int k0 = 0; k0 < 64; k0 += 4) {
        float4 av[4], bv[8];
        #pragma unroll
        for (int i = 0; i < 4; ++i) av[i] = *(const float4*)&Ra[(nl + 16 * i) * lda + k0];
        #pragma unroll
        for (int j = 0; j < 8; ++j) bv[j] = *(const float4*)&Rb[(ml + 8 * j) * ldb + k0];
        #pragma unroll
        for (int i = 0; i < 4; ++i)
            #pragma unroll
            for (int j = 0; j < 8; ++j)
                acc[i * 8 + j] += av[i].x * bv[j].x + av[i].y * bv[j].y
                                + av[i].z * bv[j].z + av[i].w * bv[j].w;
    }
}

__device__ __forceinline__ void write_half(float* X, const float* acc) {
    int lt = threadIdx.x & 127;
    int nl = lt >> 3, ml = lt & 7;
    #pragma unroll
    for (int i = 0; i < 4; ++i)
        #pragma unroll
        for (int j = 0; j < 8; ++j)
            X[(nl + 16 * i) * XLD + ml + 8 * j] = acc[i * 8 + j];
}

// full-block mm (k=64) + global store + fused loss from registers
__device__ __forceinline__ void mm256_store_loss(const float* XA, const float* XB,
                                                 float* __restrict__ aa,
                                                 float* __restrict__ out, float* red) {
    int tid = threadIdx.x;
    int nl = tid >> 4, ml = tid & 15;
    float acc[16];
    #pragma unroll
    for (int i = 0; i < 16; ++i) acc[i] = 0.f;
    #pragma unroll 4
    for (int k0 = 0; k0 < 64; k0 += 4) {
        float4 av[4], bv[4];
        #pragma unroll
        for (int i = 0; i < 4; ++i) av[i] = *(const float4*)&XA[(nl + 16 * i) * XLD + k0];
        #pragma unroll
        for (int j = 0; j < 4; ++j) bv[j] = *(const float4*)&XB[(ml + 16 * j) * XLD + k0];
        #pragma unroll
        for (int i = 0; i < 4; ++i)
            #pragma unroll
            for (int j = 0; j < 4; ++j)
                acc[i * 4 + j] += av[i].x * bv[j].x + av[i].y * bv[j].y
                                + av[i].z * bv[j].z + av[i].w * bv[j].w;
    }
    #pragma unroll
    for (int i = 0; i < 4; ++i)
        #pragma unroll
        for (int j = 0; j < 4; ++j)
            aa[(nl + 16 * i) * 64 + (ml + 16 * j)] = acc[i * 4 + j];

    // loss: rows n = nl+16i live on the 16-lane group sharing nl; diag at ml==nl
    int l = tid & 63;
    float part = 0.f;
    #pragma unroll
    for (int i = 0; i < 4; ++i) {
        float rsum = acc[i * 4 + 0] + acc[i * 4 + 1] + acc[i * 4 + 2] + acc[i * 4 + 3];
        rsum += __shfl_down(rsum, 8, 16);
        rsum += __shfl_down(rsum, 4, 16);
        rsum += __shfl_down(rsum, 2, 16);
        rsum += __shfl_down(rsum, 1, 16);
        float dv = __shfl(acc[5 * i], (l & 48) | nl, 64);
        if ((l & 15) == 0) part += logf(rsum + 6.4e-19f) - logf(dv + 1e-20f);
    }
    for (int off = 32; off; off >>= 1) part += __shfl_down(part, off);
    if (l == 0) red[tid >> 6] = part;
    __syncthreads();
    if (tid == 0) atomicAdd(out, (red[0] + red[1] + red[2] + red[3]) * (1.f / 128.f));
}

// grid = 4 (b, path), block = 256.
// r1 (halves):  P = A12_0 @ A12_1            R1T = (A21_1 @ A21_0)^T
// path0:        aa1 = P @ R1                  (mm256 with Rb = R1T)
// path1 r2:     L = P @ A12_2        ||       RT = (A21_2 @ R1)^T = R1T @ "A21_2 rows"
//       r3:     aa2 = L @ R                   (mm256 with Rb = RT)
__global__ void __launch_bounds__(256, 1)
k_chain(const float* __restrict__ a12, const float* __restrict__ a12T,
        const float* __restrict__ a21, const float* __restrict__ a21T,
        float* __restrict__ out) {
    int path = blockIdx.x & 1, b = blockIdx.x >> 1;
    __shared__ float XA[64 * XLD], XB[64 * XLD];
    __shared__ float red[4];
    const float* A12  = a12  + b * 3 * 4096;
    const float* A12T = a12T + b * 3 * 4096;
    const float* A21  = a21  + b * 3 * 4096;
    const float* A21T = a21T + b * 3 * 4096;
    int half = threadIdx.x >> 7;

    float hacc[32];
    #pragma unroll
    for (int i = 0; i < 32; ++i) hacc[i] = 0.f;
    if (half == 0) mmh_acc(hacc, A12, 64, A12T + 4096, 64);      // P
    else           mmh_acc(hacc, A21T, 64, A21 + 4096, 64);      // R1T
    write_half(half == 0 ? XA : XB, hacc);
    __syncthreads();

    if (path == 0) {
        mm256_store_loss(XA, XB, out + 1 + b * 4096, out, red);
    } else {
        #pragma unroll
        for (int i = 0; i < 32; ++i) hacc[i] = 0.f;
        if (half == 0) mmh_acc(hacc, XA, XLD, A12T + 2 * 4096, 64);   // L
        else           mmh_acc(hacc, XB, XLD, A21 + 2 * 4096, 64);    // RT
        __syncthreads();
        write_half(half == 0 ? XA : XB, hacc);
        __syncthreads();
        mm256_store_loss(XA, XB, out + 1 + (2 + b) * 4096, out, red);
    }
}

// ---------------------------------------------------------------------------
extern "C" void kernel_launch(void* const* d_in, const int* in_sizes, int n_in,
                              void* d_out, int out_size, void* d_ws, size_t ws_size,
                              hipStream_t stream) {
    const float* feats = (const float*)d_in[0];
    const float* Wh    = (const float*)d_in[1];
    const int*   mask  = (const int*)d_in[2];
    float* out = (float*)d_out;
    float* ws  = (float*)d_ws;

    float* ws_sums = ws + OFF_WS;
    float* q       = ws + OFF_Q;
    float* a12     = ws + OFF_A12;
    float* a12T    = ws + OFF_A12T;
    float* a21     = ws + OFF_A21;
    float* a21T    = ws + OFF_A21T;

    k_front<<<392 + 2 * NWIN, 256, 0, stream>>>(mask, feats, Wh, ws_sums, q);
    k_as<<<6, 256, 0, stream>>>(q, ws_sums, a12, a12T, a21, a21T, out);
    k_chain<<<4, 256, 0, stream>>>(a12, a12T, a21, a21T, out);
}

// Round 5
// 134.983 us; speedup vs baseline: 1.3933x; 1.3933x over previous
//
#include <hip/hip_runtime.h>
#include <hip/hip_bf16.h>

// Problem constants (fixed by reference setup_inputs)
constexpr int NWIN = 49;     // 7x7 windows
constexpr int QLD  = 52;     // padded row length for 49-length rows (13 float4)
constexpr int XLD  = 68;     // chain LDS tile stride (2-way conflict = free)

// workspace layout (float offsets)
constexpr int OFF_WS   = 0;            // [8][64][52]      = 26624 (bt, s, win)
constexpr int OFF_Q    = 26624;        // [2][128][4][52]  = 53248 (b, d, t, n)
constexpr int OFF_QSP  = 79872;        // [2][4][128][64]  = 65536 (b, t, d, s)
constexpr int OFF_A12  = 145408;       // [2][3][64][64]
constexpr int OFF_A12T = 169984;
constexpr int OFF_A21  = 194560;
constexpr int OFF_A21T = 219136;       // end = 243712 floats (~975 KB)

// ---------------------------------------------------------------------------
// K1: fused front end — blocks [0,392): scatter; blocks [392,490): q head.
// The two stages are data-independent and run concurrently.
__global__ void __launch_bounds__(256, 1)
k_front(const int* __restrict__ mask, const float* __restrict__ feats,
        const float* __restrict__ Wh, float* __restrict__ ws, float* __restrict__ q) {
    if (blockIdx.x < 392) {
        // ---- scatter: ws[bt][s][win] = sum over window pixels with label s of 1/sm.
        // sum_win ws[bt][s][:] == pixel count of label s (coverage * 1/sm == 1),
        // so the qsp denominator is just the row sum. Pad cols 49..51 zeroed.
        int win = blockIdx.x % NWIN;
        int bt  = blockIdx.x / NWIN;
        int wy = win / 7, wx = win % 7;
        __shared__ float loc[64];
        if (threadIdx.x < 64) loc[threadIdx.x] = 0.f;
        __syncthreads();
        const int* base = mask + bt * 65536 + (wy * 32) * 256 + wx * 32;
        #pragma unroll
        for (int it = 0; it < 16; ++it) {
            int idx = it * 256 + (int)threadIdx.x;
            int r = idx >> 6, c = idx & 63;
            int s = base[r * 256 + c];
            int y = wy * 32 + r, x = wx * 32 + c;
            float w = 1.f;
            if (y >= 32 && y < 224) w *= 0.5f;   // row coverage = 2
            if (x >= 32 && x < 224) w *= 0.5f;   // col coverage = 2
            atomicAdd(&loc[s], w);
        }
        __syncthreads();
        if (threadIdx.x < 64) {
            ws[(bt * 64 + (int)threadIdx.x) * QLD + win] = loc[threadIdx.x];
        } else if (win == 0) {
            int s = threadIdx.x & 63;
            int col = 49 + (int)(threadIdx.x >> 6) - 1;   // 49,50,51
            ws[(bt * 64 + s) * QLD + col] = 0.f;
        }
    } else {
        // ---- q head: q[b][d][t][n] = normalize_d(feats[b,n,:,t] @ Wh[:,d])
        int bid = blockIdx.x - 392;
        int n = bid % NWIN, b = bid / NWIN;
        __shared__ float4 f4[512];        // feats[c][t] as float4 over t
        __shared__ float4 psum4[256];
        __shared__ float4 red4[2];
        const float4* fp4 = (const float4*)(feats + (size_t)(b * NWIN + n) * 2048);
        for (int i = threadIdx.x; i < 512; i += 256) f4[i] = fp4[i];
        __syncthreads();

        int d = threadIdx.x & 127, ch = threadIdx.x >> 7;
        float a0 = 0.f, a1 = 0.f, a2 = 0.f, a3 = 0.f;
        const float* wp = Wh + d;
        int c0 = ch * 256;
        #pragma unroll 8
        for (int c = c0; c < c0 + 256; ++c) {
            float w = wp[c * 128];
            float4 fv = f4[c];
            a0 += fv.x * w; a1 += fv.y * w; a2 += fv.z * w; a3 += fv.w * w;
        }
        psum4[threadIdx.x] = make_float4(a0, a1, a2, a3);
        __syncthreads();

        float4 A;
        if (threadIdx.x < 128) {
            float4 p0 = psum4[threadIdx.x], p1 = psum4[128 + threadIdx.x];
            A = make_float4(p0.x + p1.x, p0.y + p1.y, p0.z + p1.z, p0.w + p1.w);
            float sx = A.x * A.x, sy = A.y * A.y, sz = A.z * A.z, sw = A.w * A.w;
            for (int off = 32; off; off >>= 1) {
                sx += __shfl_down(sx, off); sy += __shfl_down(sy, off);
                sz += __shfl_down(sz, off); sw += __shfl_down(sw, off);
            }
            if ((threadIdx.x & 63) == 0) red4[threadIdx.x >> 6] = make_float4(sx, sy, sz, sw);
        }
        __syncthreads();
        if (threadIdx.x < 128) {
            float4 r0 = red4[0], r1 = red4[1];
            float ix = 1.f / fmaxf(sqrtf(r0.x + r1.x), 1e-12f);
            float iy = 1.f / fmaxf(sqrtf(r0.y + r1.y), 1e-12f);
            float iz = 1.f / fmaxf(sqrtf(r0.z + r1.z), 1e-12f);
            float iw = 1.f / fmaxf(sqrtf(r0.w + r1.w), 1e-12f);
            float* qb = q + (size_t)(b * 128 + d) * 4 * QLD + n;
            qb[0 * QLD] = A.x * ix;
            qb[1 * QLD] = A.y * iy;
            qb[2 * QLD] = A.z * iz;
            qb[3 * QLD] = A.w * iw;
        }
    }
}

// ---------------------------------------------------------------------------
// K2: qsp[b][t][d][s] = (sum_n q[b,d,t,n]*ws[bt,s,n]) / (sum_n ws[bt,s,n]+1e-20)
// grid = 256, block = 256 — one thread per output; massive TLP hides the
// broadcast-load latency that killed the round-4 fused version.
// q rows are wave-uniform (broadcast); ws rows per-lane. Pads are zero in ws,
// so float4 over 52 cols is exact.
__global__ void k_qsp(const float* __restrict__ q, const float* __restrict__ wsg,
                      float* __restrict__ qsp) {
    int tid = blockIdx.x * 256 + threadIdx.x;   // ((b*4+t)*128+d)*64+s
    int s = tid & 63;
    int d = (tid >> 6) & 127;
    int t = (tid >> 13) & 3;
    int b = tid >> 15;
    const float4* qrow = (const float4*)(q + (size_t)((b * 128 + d) * 4 + t) * QLD);
    const float4* wrow = (const float4*)(wsg + (size_t)((b * 4 + t) * 64 + s) * QLD);
    float acc = 0.f, den = 0.f;
    #pragma unroll
    for (int i = 0; i < 13; ++i) {
        float4 w = wrow[i];
        float4 qv = qrow[i];
        den += w.x + w.y + w.z + w.w;
        acc += qv.x * w.x + qv.y * w.y + qv.z * w.z + qv.w * w.w;
    }
    qsp[tid] = acc / (den + 1e-20f);
}

// ---------------------------------------------------------------------------
// K3: As + zero_softmax. grid = 6 (b, t-pair), block = 256.
// Stages qsp slices (coalesced float4) into XOR-swizzled LDS [s][d], then one
// k=128 4x4-tile mm, zero_softmax both ways, emit a12/a12T/a21/a21T.
__global__ void __launch_bounds__(256, 1)
k_as(const float* __restrict__ qsp,
     float* __restrict__ a12, float* __restrict__ a12T,
     float* __restrict__ a21, float* __restrict__ a21T, float* __restrict__ out) {
    int t = blockIdx.x % 3, b = blockIdx.x / 3;
    if (blockIdx.x == 0 && threadIdx.x == 0) out[0] = 0.f;   // loss accumulator
    __shared__ float4 qaT4[64 * 32];   // [s][d-swizzled]: float4 u <-> d=4g+u
    __shared__ float4 qbT4[64 * 32];
    const int tid = threadIdx.x;

    // stage + transpose: global [d][s] (float4 over s) -> LDS [s][d] swizzled
    {
        const float4* gA = (const float4*)(qsp + (size_t)(b * 4 + t) * 8192);
        const float4* gB = (const float4*)(qsp + (size_t)(b * 4 + t + 1) * 8192);
        float* qaF = (float*)qaT4;
        float* qbF = (float*)qbT4;
        #pragma unroll
        for (int it = 0; it < 8; ++it) {
            int idx = it * 256 + tid;           // float4 index over [d][s/4]
            int d = idx >> 4, s0 = (idx & 15) << 2;
            float4 va = gA[idx];
            float4 vb = gB[idx];
            int g = d >> 2, c = d & 3;
            #pragma unroll
            for (int u = 0; u < 4; ++u) {
                int s = s0 + u;
                int w = (s * 32 + (g ^ (s & 31))) * 4 + c;
                float fa = (u == 0) ? va.x : (u == 1) ? va.y : (u == 2) ? va.z : va.w;
                float fb = (u == 0) ? vb.x : (u == 1) ? vb.y : (u == 2) ? vb.z : vb.w;
                qaF[w] = fa;
                qbF[w] = fb;
            }
        }
    }
    __syncthreads();

    // As[n,m] = sum_d qspA[d,n] * qspB[d,m]  (k = 128)
    const int nl = tid >> 4, ml = tid & 15;
    float acc[16];
    #pragma unroll
    for (int i = 0; i < 16; ++i) acc[i] = 0.f;
    #pragma unroll 8
    for (int k4 = 0; k4 < 32; ++k4) {
        float4 av[4], bv[4];
        #pragma unroll
        for (int i = 0; i < 4; ++i) { int n = nl + 16 * i; av[i] = qaT4[n * 32 + (k4 ^ (n & 31))]; }
        #pragma unroll
        for (int j = 0; j < 4; ++j) { int m = ml + 16 * j; bv[j] = qbT4[m * 32 + (k4 ^ (m & 31))]; }
        #pragma unroll
        for (int i = 0; i < 4; ++i)
            #pragma unroll
            for (int j = 0; j < 4; ++j)
                acc[i * 4 + j] += av[i].x * bv[j].x + av[i].y * bv[j].y
                                + av[i].z * bv[j].z + av[i].w * bv[j].w;
    }
    __syncthreads();

    // zero_softmax both ways; emit a12, a12T, a21, a21T
    float* eb = (float*)qaT4;          // [64][65]
    float* rs = (float*)qbT4;          // [64]
    float* cs = rs + 64;               // [64]
    #pragma unroll
    for (int i = 0; i < 4; ++i)
        #pragma unroll
        for (int j = 0; j < 4; ++j) {
            int n = nl + 16 * i, m = ml + 16 * j;
            float x = acc[i * 4 + j] * (1.f / 0.07f);
            float e = expf(x) - 1.f;
            eb[n * 65 + m] = e * e;
        }
    __syncthreads();
    if (tid < 128) {
        int r = tid & 63; bool isrow = tid < 64;
        float a = 0.f;
        #pragma unroll
        for (int k = 0; k < 64; ++k) a += isrow ? eb[r * 65 + k] : eb[k * 65 + r];
        (isrow ? rs : cs)[r] = a + 1e-5f;
    }
    __syncthreads();
    float* p12  = a12  + (b * 3 + t) * 4096;
    float* p12T = a12T + (b * 3 + t) * 4096;
    float* p21  = a21  + (b * 3 + t) * 4096;
    float* p21T = a21T + (b * 3 + t) * 4096;
    #pragma unroll
    for (int i = 0; i < 4; ++i)
        #pragma unroll
        for (int j = 0; j < 4; ++j) {
            int n = nl + 16 * i, m = ml + 16 * j;
            float v   = eb[n * 65 + m];
            float v12 = v / rs[n];           // A12[n][m]
            float v21 = v / cs[m];           // A21[m][n]
            p12 [n * 64 + m] = v12;
            p12T[m * 64 + n] = v12;
            p21 [m * 64 + n] = v21;
            p21T[n * 64 + m] = v21;          // A21^T[n][m]
        }
}

// ---------------------------------------------------------------------------
// K4: chain matmuls, depth 3 via parallel half-block subchains.
// half-mm (128 threads, 4x8 tiles): operands from global (L2-hot) or LDS.
__device__ __forceinline__ void mmh_acc(float* acc, const float* Ra, int lda,
                                        const float* Rb, int ldb) {
    int lt = threadIdx.x & 127;
    int nl = lt >> 3, ml = lt & 7;
    #pragma unroll 4
    for (int k0 = 0; k0 < 64; k0 += 4) {
        float4 av[4], bv[8];
        #pragma unroll
        for (int i = 0; i < 4; ++i) av[i] = *(const float4*)&Ra[(nl + 16 * i) * lda + k0];
        #pragma unroll
        for (int j = 0; j < 8; ++j) bv[j] = *(const float4*)&Rb[(ml + 8 * j) * ldb + k0];
        #pragma unroll
        for (int i = 0; i < 4; ++i)
            #pragma unroll
            for (int j = 0; j < 8; ++j)
                acc[i * 8 + j] += av[i].x * bv[j].x + av[i].y * bv[j].y
                                + av[i].z * bv[j].z + av[i].w * bv[j].w;
    }
}

__device__ __forceinline__ void write_half(float* X, const float* acc) {
    int lt = threadIdx.x & 127;
    int nl = lt >> 3, ml = lt & 7;
    #pragma unroll
    for (int i = 0; i < 4; ++i)
        #pragma unroll
        for (int j = 0; j < 8; ++j)
            X[(nl + 16 * i) * XLD + ml + 8 * j] = acc[i * 8 + j];
}

// full-block mm (k=64) + global store + fused loss from registers
__device__ __forceinline__ void mm256_store_loss(const float* XA, const float* XB,
                                                 float* __restrict__ aa,
                                                 float* __restrict__ out, float* red) {
    int tid = threadIdx.x;
    int nl = tid >> 4, ml = tid & 15;
    float acc[16];
    #pragma unroll
    for (int i = 0; i < 16; ++i) acc[i] = 0.f;
    #pragma unroll 4
    for (int k0 = 0; k0 < 64; k0 += 4) {
        float4 av[4], bv[4];
        #pragma unroll
        for (int i = 0; i < 4; ++i) av[i] = *(const float4*)&XA[(nl + 16 * i) * XLD + k0];
        #pragma unroll
        for (int j = 0; j < 4; ++j) bv[j] = *(const float4*)&XB[(ml + 16 * j) * XLD + k0];
        #pragma unroll
        for (int i = 0; i < 4; ++i)
            #pragma unroll
            for (int j = 0; j < 4; ++j)
                acc[i * 4 + j] += av[i].x * bv[j].x + av[i].y * bv[j].y
                                + av[i].z * bv[j].z + av[i].w * bv[j].w;
    }
    #pragma unroll
    for (int i = 0; i < 4; ++i)
        #pragma unroll
        for (int j = 0; j < 4; ++j)
            aa[(nl + 16 * i) * 64 + (ml + 16 * j)] = acc[i * 4 + j];

    // loss: rows n = nl+16i live on the 16-lane group sharing nl; diag at ml==nl
    int l = tid & 63;
    float part = 0.f;
    #pragma unroll
    for (int i = 0; i < 4; ++i) {
        float rsum = acc[i * 4 + 0] + acc[i * 4 + 1] + acc[i * 4 + 2] + acc[i * 4 + 3];
        rsum += __shfl_down(rsum, 8, 16);
        rsum += __shfl_down(rsum, 4, 16);
        rsum += __shfl_down(rsum, 2, 16);
        rsum += __shfl_down(rsum, 1, 16);
        float dv = __shfl(acc[5 * i], (l & 48) | nl, 64);
        if ((l & 15) == 0) part += logf(rsum + 6.4e-19f) - logf(dv + 1e-20f);
    }
    for (int off = 32; off; off >>= 1) part += __shfl_down(part, off);
    if (l == 0) red[tid >> 6] = part;
    __syncthreads();
    if (tid == 0) atomicAdd(out, (red[0] + red[1] + red[2] + red[3]) * (1.f / 128.f));
}

// grid = 4 (b, path), block = 256.
// r1 (halves):  P = A12_0 @ A12_1            R1T = (A21_1 @ A21_0)^T
// path0:        aa1 = P @ R1                  (mm256 with Rb = R1T)
// path1 r2:     L = P @ A12_2        ||       RT = R1T @ A21_2-rows
//       r3:     aa2 = L @ R                   (mm256 with Rb = RT)
__global__ void __launch_bounds__(256, 1)
k_chain(const float* __restrict__ a12, const float* __restrict__ a12T,
        const float* __restrict__ a21, const float* __restrict__ a21T,
        float* __restrict__ out) {
    int path = blockIdx.x & 1, b = blockIdx.x >> 1;
    __shared__ float XA[64 * XLD], XB[64 * XLD];
    __shared__ float red[4];
    const float* A12  = a12  + b * 3 * 4096;
    const float* A12T = a12T + b * 3 * 4096;
    const float* A21  = a21  + b * 3 * 4096;
    const float* A21T = a21T + b * 3 * 4096;
    int half = threadIdx.x >> 7;

    float hacc[32];
    #pragma unroll
    for (int i = 0; i < 32; ++i) hacc[i] = 0.f;
    if (half == 0) mmh_acc(hacc, A12, 64, A12T + 4096, 64);      // P
    else           mmh_acc(hacc, A21T, 64, A21 + 4096, 64);      // R1T
    write_half(half == 0 ? XA : XB, hacc);
    __syncthreads();

    if (path == 0) {
        mm256_store_loss(XA, XB, out + 1 + b * 4096, out, red);
    } else {
        #pragma unroll
        for (int i = 0; i < 32; ++i) hacc[i] = 0.f;
        if (half == 0) mmh_acc(hacc, XA, XLD, A12T + 2 * 4096, 64);   // L
        else           mmh_acc(hacc, XB, XLD, A21 + 2 * 4096, 64);    // RT
        __syncthreads();
        write_half(half == 0 ? XA : XB, hacc);
        __syncthreads();
        mm256_store_loss(XA, XB, out + 1 + (2 + b) * 4096, out, red);
    }
}

// ---------------------------------------------------------------------------
extern "C" void kernel_launch(void* const* d_in, const int* in_sizes, int n_in,
                              void* d_out, int out_size, void* d_ws, size_t ws_size,
                              hipStream_t stream) {
    const float* feats = (const float*)d_in[0];
    const float* Wh    = (const float*)d_in[1];
    const int*   mask  = (const int*)d_in[2];
    float* out = (float*)d_out;
    float* ws  = (float*)d_ws;

    float* ws_sums = ws + OFF_WS;
    float* q       = ws + OFF_Q;
    float* qsp     = ws + OFF_QSP;
    float* a12     = ws + OFF_A12;
    float* a12T    = ws + OFF_A12T;
    float* a21     = ws + OFF_A21;
    float* a21T    = ws + OFF_A21T;

    k_front<<<392 + 2 * NWIN, 256, 0, stream>>>(mask, feats, Wh, ws_sums, q);
    k_qsp<<<256, 256, 0, stream>>>(q, ws_sums, qsp);
    k_as<<<6, 256, 0, stream>>>(qsp, a12, a12T, a21, a21T, out);
    k_chain<<<4, 256, 0, stream>>>(a12, a12T, a21, a21T, out);
}

// Round 6
// 118.305 us; speedup vs baseline: 1.5897x; 1.1410x over previous
//
#include <hip/hip_runtime.h>
#include <hip/hip_bf16.h>

// Problem constants (fixed by reference setup_inputs)
constexpr int NWIN = 49;     // 7x7 windows
constexpr int QLD  = 52;     // padded row length for 49-length rows (13 float4)

// workspace layout (float offsets)
constexpr int OFF_WS   = 0;            // [8][64][52]      = 26624 (bt, s, win)
constexpr int OFF_Q    = 26624;        // [2][128][4][52]  = 53248 (b, d, t, n)
constexpr int OFF_QSP  = 79872;        // [2][4][128][64]  = 65536 (b, t, d, s)
constexpr int OFF_A12  = 145408;       // [2][3][64][64]
constexpr int OFF_A12T = 169984;
constexpr int OFF_A21  = 194560;
constexpr int OFF_A21T = 219136;       // end = 243712 floats (~975 KB)

// ---------------------------------------------------------------------------
// K1: fused front end — blocks [0,392): scatter; blocks [392,490): q head.
__global__ void __launch_bounds__(256, 1)
k_front(const int* __restrict__ mask, const float* __restrict__ feats,
        const float* __restrict__ Wh, float* __restrict__ ws, float* __restrict__ q) {
    if (blockIdx.x < 392) {
        // ws[bt][s][win] = sum over window pixels with label s of 1/sm.
        // sum_win ws[bt][s][:] == pixel count of label s, so the qsp
        // denominator is just the row sum. Pad cols 49..51 zeroed.
        int win = blockIdx.x % NWIN;
        int bt  = blockIdx.x / NWIN;
        int wy = win / 7, wx = win % 7;
        __shared__ float loc[64];
        if (threadIdx.x < 64) loc[threadIdx.x] = 0.f;
        __syncthreads();
        const int* base = mask + bt * 65536 + (wy * 32) * 256 + wx * 32;
        #pragma unroll
        for (int it = 0; it < 16; ++it) {
            int idx = it * 256 + (int)threadIdx.x;
            int r = idx >> 6, c = idx & 63;
            int s = base[r * 256 + c];
            int y = wy * 32 + r, x = wx * 32 + c;
            float w = 1.f;
            if (y >= 32 && y < 224) w *= 0.5f;   // row coverage = 2
            if (x >= 32 && x < 224) w *= 0.5f;   // col coverage = 2
            atomicAdd(&loc[s], w);
        }
        __syncthreads();
        if (threadIdx.x < 64) {
            ws[(bt * 64 + (int)threadIdx.x) * QLD + win] = loc[threadIdx.x];
        } else if (win == 0) {
            int s = threadIdx.x & 63;
            int col = 49 + (int)(threadIdx.x >> 6) - 1;   // 49,50,51
            ws[(bt * 64 + s) * QLD + col] = 0.f;
        }
    } else {
        // q[b][d][t][n] = normalize_d(feats[b,n,:,t] @ Wh[:,d])
        int bid = blockIdx.x - 392;
        int n = bid % NWIN, b = bid / NWIN;
        __shared__ float4 f4[512];        // feats[c][t] as float4 over t
        __shared__ float4 psum4[256];
        __shared__ float4 red4[2];
        const float4* fp4 = (const float4*)(feats + (size_t)(b * NWIN + n) * 2048);
        for (int i = threadIdx.x; i < 512; i += 256) f4[i] = fp4[i];
        __syncthreads();

        int d = threadIdx.x & 127, ch = threadIdx.x >> 7;
        float a0 = 0.f, a1 = 0.f, a2 = 0.f, a3 = 0.f;
        const float* wp = Wh + d;
        int c0 = ch * 256;
        #pragma unroll 8
        for (int c = c0; c < c0 + 256; ++c) {
            float w = wp[c * 128];
            float4 fv = f4[c];
            a0 += fv.x * w; a1 += fv.y * w; a2 += fv.z * w; a3 += fv.w * w;
        }
        psum4[threadIdx.x] = make_float4(a0, a1, a2, a3);
        __syncthreads();

        float4 A;
        if (threadIdx.x < 128) {
            float4 p0 = psum4[threadIdx.x], p1 = psum4[128 + threadIdx.x];
            A = make_float4(p0.x + p1.x, p0.y + p1.y, p0.z + p1.z, p0.w + p1.w);
            float sx = A.x * A.x, sy = A.y * A.y, sz = A.z * A.z, sw = A.w * A.w;
            for (int off = 32; off; off >>= 1) {
                sx += __shfl_down(sx, off); sy += __shfl_down(sy, off);
                sz += __shfl_down(sz, off); sw += __shfl_down(sw, off);
            }
            if ((threadIdx.x & 63) == 0) red4[threadIdx.x >> 6] = make_float4(sx, sy, sz, sw);
        }
        __syncthreads();
        if (threadIdx.x < 128) {
            float4 r0 = red4[0], r1 = red4[1];
            float ix = 1.f / fmaxf(sqrtf(r0.x + r1.x), 1e-12f);
            float iy = 1.f / fmaxf(sqrtf(r0.y + r1.y), 1e-12f);
            float iz = 1.f / fmaxf(sqrtf(r0.z + r1.z), 1e-12f);
            float iw = 1.f / fmaxf(sqrtf(r0.w + r1.w), 1e-12f);
            float* qb = q + (size_t)(b * 128 + d) * 4 * QLD + n;
            qb[0 * QLD] = A.x * ix;
            qb[1 * QLD] = A.y * iy;
            qb[2 * QLD] = A.z * iz;
            qb[3 * QLD] = A.w * iw;
        }
    }
}

// ---------------------------------------------------------------------------
// K2: qsp[b][t][d][s] = (sum_n q[b,d,t,n]*ws[bt,s,n]) / (sum_n ws[bt,s,n]+1e-20)
// grid = 256, block = 256 — one thread per output (TLP hides broadcast latency).
__global__ void k_qsp(const float* __restrict__ q, const float* __restrict__ wsg,
                      float* __restrict__ qsp) {
    int tid = blockIdx.x * 256 + threadIdx.x;   // ((b*4+t)*128+d)*64+s
    int s = tid & 63;
    int d = (tid >> 6) & 127;
    int t = (tid >> 13) & 3;
    int b = tid >> 15;
    const float4* qrow = (const float4*)(q + (size_t)((b * 128 + d) * 4 + t) * QLD);
    const float4* wrow = (const float4*)(wsg + (size_t)((b * 4 + t) * 64 + s) * QLD);
    float acc = 0.f, den = 0.f;
    #pragma unroll
    for (int i = 0; i < 13; ++i) {
        float4 w = wrow[i];
        float4 qv = qrow[i];
        den += w.x + w.y + w.z + w.w;
        acc += qv.x * w.x + qv.y * w.y + qv.z * w.z + qv.w * w.w;
    }
    qsp[tid] = acc / (den + 1e-20f);
}

// ---------------------------------------------------------------------------
// K3: As + zero_softmax. grid = 6 (b, t-pair), block = 256. (unchanged, proven)
__global__ void __launch_bounds__(256, 1)
k_as(const float* __restrict__ qsp,
     float* __restrict__ a12, float* __restrict__ a12T,
     float* __restrict__ a21, float* __restrict__ a21T, float* __restrict__ out) {
    int t = blockIdx.x % 3, b = blockIdx.x / 3;
    if (blockIdx.x == 0 && threadIdx.x == 0) out[0] = 0.f;   // loss accumulator
    __shared__ float4 qaT4[64 * 32];   // [s][d-swizzled]
    __shared__ float4 qbT4[64 * 32];
    const int tid = threadIdx.x;

    {
        const float4* gA = (const float4*)(qsp + (size_t)(b * 4 + t) * 8192);
        const float4* gB = (const float4*)(qsp + (size_t)(b * 4 + t + 1) * 8192);
        float* qaF = (float*)qaT4;
        float* qbF = (float*)qbT4;
        #pragma unroll
        for (int it = 0; it < 8; ++it) {
            int idx = it * 256 + tid;           // float4 index over [d][s/4]
            int d = idx >> 4, s0 = (idx & 15) << 2;
            float4 va = gA[idx];
            float4 vb = gB[idx];
            int g = d >> 2, c = d & 3;
            #pragma unroll
            for (int u = 0; u < 4; ++u) {
                int s = s0 + u;
                int w = (s * 32 + (g ^ (s & 31))) * 4 + c;
                float fa = (u == 0) ? va.x : (u == 1) ? va.y : (u == 2) ? va.z : va.w;
                float fb = (u == 0) ? vb.x : (u == 1) ? vb.y : (u == 2) ? vb.z : vb.w;
                qaF[w] = fa;
                qbF[w] = fb;
            }
        }
    }
    __syncthreads();

    const int nl = tid >> 4, ml = tid & 15;
    float acc[16];
    #pragma unroll
    for (int i = 0; i < 16; ++i) acc[i] = 0.f;
    #pragma unroll 8
    for (int k4 = 0; k4 < 32; ++k4) {
        float4 av[4], bv[4];
        #pragma unroll
        for (int i = 0; i < 4; ++i) { int n = nl + 16 * i; av[i] = qaT4[n * 32 + (k4 ^ (n & 31))]; }
        #pragma unroll
        for (int j = 0; j < 4; ++j) { int m = ml + 16 * j; bv[j] = qbT4[m * 32 + (k4 ^ (m & 31))]; }
        #pragma unroll
        for (int i = 0; i < 4; ++i)
            #pragma unroll
            for (int j = 0; j < 4; ++j)
                acc[i * 4 + j] += av[i].x * bv[j].x + av[i].y * bv[j].y
                                + av[i].z * bv[j].z + av[i].w * bv[j].w;
    }
    __syncthreads();

    float* eb = (float*)qaT4;          // [64][65]
    float* rs = (float*)qbT4;          // [64]
    float* cs = rs + 64;               // [64]
    #pragma unroll
    for (int i = 0; i < 4; ++i)
        #pragma unroll
        for (int j = 0; j < 4; ++j) {
            int n = nl + 16 * i, m = ml + 16 * j;
            float x = acc[i * 4 + j] * (1.f / 0.07f);
            float e = expf(x) - 1.f;
            eb[n * 65 + m] = e * e;
        }
    __syncthreads();
    if (tid < 128) {
        int r = tid & 63; bool isrow = tid < 64;
        float a = 0.f;
        #pragma unroll
        for (int k = 0; k < 64; ++k) a += isrow ? eb[r * 65 + k] : eb[k * 65 + r];
        (isrow ? rs : cs)[r] = a + 1e-5f;
    }
    __syncthreads();
    float* p12  = a12  + (b * 3 + t) * 4096;
    float* p12T = a12T + (b * 3 + t) * 4096;
    float* p21  = a21  + (b * 3 + t) * 4096;
    float* p21T = a21T + (b * 3 + t) * 4096;
    #pragma unroll
    for (int i = 0; i < 4; ++i)
        #pragma unroll
        for (int j = 0; j < 4; ++j) {
            int n = nl + 16 * i, m = ml + 16 * j;
            float v   = eb[n * 65 + m];
            float v12 = v / rs[n];           // A12[n][m]
            float v21 = v / cs[m];           // A21[m][n]
            p12 [n * 64 + m] = v12;
            p12T[m * 64 + n] = v12;
            p21 [m * 64 + n] = v21;
            p21T[n * 64 + m] = v21;          // A21^T[n][m]
        }
}

// ---------------------------------------------------------------------------
// K4: chain matmuls v4 — all leaf operands prefetched coalesced into registers
// at kernel entry (MLP 24), dumped to XOR-4-swizzled LDS (4 x 16 KB = 64 KB,
// zero padding, <=2-way banks). Every mm reads LDS only — no global gathers.
// Layout: element (r,k) of a matrix lives at M[r*64 + (((k>>2)^(r&15))<<2)+(k&3)].

__device__ __forceinline__ void dump_mat(float* M, const float4* v) {
    #pragma unroll
    for (int it = 0; it < 4; ++it) {
        int idx = it * 256 + (int)threadIdx.x;
        int r = idx >> 4, c4 = (idx & 15) << 2;
        *(float4*)&M[r * 64 + (c4 ^ ((r & 15) << 2))] = v[it];
    }
}

// half-block mm (128 threads, 4x8 tiles), swizzled LDS operands (both B^T-rows)
__device__ __forceinline__ void mmh_sw(float* acc, const float* Ra, const float* Rb) {
    int lt = threadIdx.x & 127;
    int nl = lt >> 3, ml = lt & 7;
    int sxa = nl << 2;
    #pragma unroll
    for (int k0 = 0; k0 < 64; k0 += 4) {
        float4 av[4], bv[8];
        #pragma unroll
        for (int i = 0; i < 4; ++i)
            av[i] = *(const float4*)&Ra[(nl + 16 * i) * 64 + (k0 ^ sxa)];
        #pragma unroll
        for (int j = 0; j < 8; ++j) {
            int m = ml + 8 * j;
            bv[j] = *(const float4*)&Rb[m * 64 + (k0 ^ ((m & 15) << 2))];
        }
        #pragma unroll
        for (int i = 0; i < 4; ++i)
            #pragma unroll
            for (int j = 0; j < 8; ++j)
                acc[i * 8 + j] += av[i].x * bv[j].x + av[i].y * bv[j].y
                                + av[i].z * bv[j].z + av[i].w * bv[j].w;
    }
}

__device__ __forceinline__ void wrh_sw(float* M, const float* acc) {
    int lt = threadIdx.x & 127;
    int nl = lt >> 3, ml = lt & 7;
    #pragma unroll
    for (int i = 0; i < 4; ++i)
        #pragma unroll
        for (int j = 0; j < 8; ++j) {
            int r = nl + 16 * i, k = ml + 8 * j;
            M[r * 64 + (((k & ~3) ^ ((r & 15) << 2)) | (k & 3))] = acc[i * 8 + j];
        }
}

// full-block mm (k=64, 4x4 tiles), swizzled LDS operands
__device__ __forceinline__ void mm256_sw(float* acc, const float* Ra, const float* Rb) {
    int tid = threadIdx.x;
    int nl = tid >> 4, ml = tid & 15;
    int sxa = nl << 2, sxb = ml << 2;
    #pragma unroll
    for (int i = 0; i < 16; ++i) acc[i] = 0.f;
    #pragma unroll 4
    for (int k0 = 0; k0 < 64; k0 += 4) {
        float4 av[4], bv[4];
        #pragma unroll
        for (int i = 0; i < 4; ++i)
            av[i] = *(const float4*)&Ra[(nl + 16 * i) * 64 + (k0 ^ sxa)];
        #pragma unroll
        for (int j = 0; j < 4; ++j)
            bv[j] = *(const float4*)&Rb[(ml + 16 * j) * 64 + (k0 ^ sxb)];
        #pragma unroll
        for (int i = 0; i < 4; ++i)
            #pragma unroll
            for (int j = 0; j < 4; ++j)
                acc[i * 4 + j] += av[i].x * bv[j].x + av[i].y * bv[j].y
                                + av[i].z * bv[j].z + av[i].w * bv[j].w;
    }
}

// store aa + fused loss from registers (proven epilogue)
__device__ __forceinline__ void store_loss(const float* acc, float* __restrict__ aa,
                                           float* __restrict__ out, float* red) {
    int tid = threadIdx.x;
    int nl = tid >> 4, ml = tid & 15;
    #pragma unroll
    for (int i = 0; i < 4; ++i)
        #pragma unroll
        for (int j = 0; j < 4; ++j)
            aa[(nl + 16 * i) * 64 + (ml + 16 * j)] = acc[i * 4 + j];
    int l = tid & 63;
    float part = 0.f;
    #pragma unroll
    for (int i = 0; i < 4; ++i) {
        float rsum = acc[i * 4 + 0] + acc[i * 4 + 1] + acc[i * 4 + 2] + acc[i * 4 + 3];
        rsum += __shfl_down(rsum, 8, 16);
        rsum += __shfl_down(rsum, 4, 16);
        rsum += __shfl_down(rsum, 2, 16);
        rsum += __shfl_down(rsum, 1, 16);
        float dv = __shfl(acc[5 * i], (l & 48) | nl, 64);
        if ((l & 15) == 0) part += logf(rsum + 6.4e-19f) - logf(dv + 1e-20f);
    }
    for (int off = 32; off; off >>= 1) part += __shfl_down(part, off);
    if (l == 0) red[tid >> 6] = part;
    __syncthreads();
    if (tid == 0) atomicAdd(out, (red[0] + red[1] + red[2] + red[3]) * (1.f / 128.f));
}

// grid = 4 (b, path), block = 256.
// r1 (halves):  P = A12_0 @ A12_1 -> M1      R1T = (A21_1 @ A21_0)^T -> M3
// path0:        aa1 = P @ R1                  (mm256 Ra=M1, Rb=M3)
// path1 r2:     L = P @ A12_2 -> M0    ||     RT = (A21_2@R1)^T = R1T x a21_2 -> M1
//       r3:     aa2 = L @ R                   (mm256 Ra=M0, Rb=M1)
__global__ void __launch_bounds__(256, 1)
k_chain(const float* __restrict__ a12, const float* __restrict__ a12T,
        const float* __restrict__ a21, const float* __restrict__ a21T,
        float* __restrict__ out) {
    int path = blockIdx.x & 1, b = blockIdx.x >> 1;
    __shared__ float M[4 * 4096];     // exactly 64 KB
    float* M0 = M;
    float* M1 = M + 4096;
    float* M2 = M + 8192;
    float* M3 = M + 12288;
    const int tid = threadIdx.x;

    const float4* L0 = (const float4*)(a12  + (b * 3 + 0) * 4096);  // A12_0 rows
    const float4* L1 = (const float4*)(a12T + (b * 3 + 1) * 4096);  // A12_1^T rows
    const float4* L2 = (const float4*)(a21T + (b * 3 + 0) * 4096);  // A21_0^T rows
    const float4* L3 = (const float4*)(a21  + (b * 3 + 1) * 4096);  // A21_1 rows
    const float4* L4 = (const float4*)(a12T + (b * 3 + 2) * 4096);  // A12_2^T rows
    const float4* L5 = (const float4*)(a21  + (b * 3 + 2) * 4096);  // A21_2 rows

    // coalesced prefetch of all leaves (MLP 16 or 24, latency paid once)
    float4 pf[6][4];
    #pragma unroll
    for (int it = 0; it < 4; ++it) {
        int idx = it * 256 + tid;
        pf[0][it] = L0[idx];
        pf[1][it] = L1[idx];
        pf[2][it] = L2[idx];
        pf[3][it] = L3[idx];
    }
    if (path) {
        #pragma unroll
        for (int it = 0; it < 4; ++it) {
            int idx = it * 256 + tid;
            pf[4][it] = L4[idx];
            pf[5][it] = L5[idx];
        }
    }
    dump_mat(M0, pf[0]);
    dump_mat(M1, pf[1]);
    dump_mat(M2, pf[2]);
    dump_mat(M3, pf[3]);
    __syncthreads();

    int half = tid >> 7;
    float hacc[32];
    #pragma unroll
    for (int i = 0; i < 32; ++i) hacc[i] = 0.f;
    mmh_sw(hacc, half ? M2 : M0, half ? M3 : M1);   // P | R1T
    __syncthreads();                                 // all r1 reads done
    wrh_sw(half ? M3 : M1, hacc);                    // P -> M1, R1T -> M3
    if (path) { dump_mat(M0, pf[4]); dump_mat(M2, pf[5]); }  // a12T_2, a21_2
    __syncthreads();

    if (path == 0) {
        float acc[16];
        mm256_sw(acc, M1, M3);                       // aa1 = P @ R1
        store_loss(acc, out + 1 + b * 4096, out, M0);
    } else {
        float hacc2[32];
        #pragma unroll
        for (int i = 0; i < 32; ++i) hacc2[i] = 0.f;
        mmh_sw(hacc2, half ? M3 : M1, half ? M2 : M0);  // L = P@A12_2 | RT = R1T x a21_2
        __syncthreads();
        wrh_sw(half ? M1 : M0, hacc2);                  // L -> M0, RT -> M1
        __syncthreads();
        float acc[16];
        mm256_sw(acc, M0, M1);                          // aa2 = L @ R
        store_loss(acc, out + 1 + (2 + b) * 4096, out, M2);
    }
}

// ---------------------------------------------------------------------------
extern "C" void kernel_launch(void* const* d_in, const int* in_sizes, int n_in,
                              void* d_out, int out_size, void* d_ws, size_t ws_size,
                              hipStream_t stream) {
    const float* feats = (const float*)d_in[0];
    const float* Wh    = (const float*)d_in[1];
    const int*   mask  = (const int*)d_in[2];
    float* out = (float*)d_out;
    float* ws  = (float*)d_ws;

    float* ws_sums = ws + OFF_WS;
    float* q       = ws + OFF_Q;
    float* qsp     = ws + OFF_QSP;
    float* a12     = ws + OFF_A12;
    float* a12T    = ws + OFF_A12T;
    float* a21     = ws + OFF_A21;
    float* a21T    = ws + OFF_A21T;

    k_front<<<392 + 2 * NWIN, 256, 0, stream>>>(mask, feats, Wh, ws_sums, q);
    k_qsp<<<256, 256, 0, stream>>>(q, ws_sums, qsp);
    k_as<<<6, 256, 0, stream>>>(qsp, a12, a12T, a21, a21T, out);
    k_chain<<<4, 256, 0, stream>>>(a12, a12T, a21, a21T, out);
}